// Round 4
// baseline (177.694 us; speedup 1.0000x reference)
//
#include <hip/hip_runtime.h>

// LatticeFilter: step-up (Levinson-Durbin) recursion, rc -> LPC coeffs.
//   rc: (B=16, p=128, Tf=8192) fp32, k_i = 0.98*rc[b,i,t]
//   out: (B, Tf, p+1=129) fp32, a[...,0]=1
//
// R9. R8 post-mortem CONFIRMED the I$ theory with a clean split experiment:
//   - kernel A (13KB code) ran at its BW floor (~8us, inferred: absent from
//     top-5, bench total matches 2.64x(58+8))
//   - kernel B (57KB code) = 58us, same per-FMA cost as R5's 65KB kernel
//     -> no gain from 65->57KB; the cliff is between 13KB and 57KB,
//     consistent with a 32KB L1I. True VALU busy ~11us = issue floor.
// Code must fit ~32KB or every wave-pass streams it from L2.
//
// Fix: 2-way split at S=90 with the pair update forced into v_fmac_f32
// (VOP2, 4 bytes) via inline asm: mov + 2 fmac = 12B/pair vs 16B.
//   A (steps 1..90):  ~26KB text  < 32KB I$
//   B (steps 91..128):~27KB text  < 32KB I$
// fmac is the same fused op in the same order -> bit-identical results.
// Extra movs (+50% instrs) hide under BW floors (issue 10.5/11.2us vs
// BW 15/21.4us -> both kernels memory-bound).
// State a[1..90] parks in its FINAL out positions (slot==output, no extra
// memory, no races; fp32 RT is exact). Budget: A 94.4MB -> 15us floor,
// B 134.7MB -> 21.4us floor; sum 36.4us vs R5's 52.8.

#define NB    16
#define ORD   128
#define TF    8192
#define SPLIT 90

// ---- pair update j <-> m-j, VOP2 v_fmac encoding (4B vs VOP3 fma 8B) ----
// a[J] += k*a[M-J];  a[M-J] += k*a[J]_old   (lo copy = 1 v_mov, 4B)
template<int M, int J>
struct PairUpd {
    static __device__ __forceinline__ void run(float (&a)[ORD + 1], float k) {
        const float lo = a[J];                  // old value (one v_mov)
        const float hi = a[M - J];              // aliases a[M-J]'s reg (no mov)
        asm("v_fmac_f32 %0, %1, %2" : "+v"(a[J])     : "v"(k), "v"(hi));
        asm("v_fmac_f32 %0, %1, %2" : "+v"(a[M - J]) : "v"(k), "v"(lo));
        if constexpr (2 * (J + 1) < M) PairUpd<M, J + 1>::run(a, k);
    }
};

// Steps M..MEND; k from kq[M-1-K0]
template<int M, int MEND, int K0, int NK>
struct Step {
    static __device__ __forceinline__ void run(float (&a)[ORD + 1],
                                               const float (&kq)[NK]) {
        const float k = 0.98f * kq[M - 1 - K0];
        if constexpr (M > 2) PairUpd<M, 1>::run(a, k);
        if constexpr ((M & 1) == 0) {            // middle element self-update
            const float mid = a[M / 2];
            a[M / 2] = fmaf(k, mid, mid);        // 64 total, size-negligible
        }
        a[M] = k;                                // a[0] == 1 contributes k
        if constexpr (M < MEND) Step<M + 1, MEND, K0, NK>::run(a, kq);
    }
};

// ---- LDS staging, static indices (compiler merges into ds_write_b128) ----
template<int J>
struct Stage {
    static __device__ __forceinline__ void run(float* __restrict__ dst,
                                               const float (&a)[ORD + 1]) {
        dst[J] = a[J];
        if constexpr (J < ORD) Stage<J + 1>::run(dst, a);
    }
};

// =======================  Kernel A: steps 1..SPLIT  =======================
// ~26KB text. Writes a[1..SPLIT] to out[col*129 + j] (final positions).
__global__ __launch_bounds__(256)
void lpc_stepA(const float* __restrict__ rc, float* __restrict__ out) {
    const int col = blockIdx.x * 256 + threadIdx.x;   // flattened (B*Tf) column
    const int b = col >> 13;
    const int t = col & (TF - 1);
    const float* rcp = rc + ((size_t)b * ORD) * TF + t;

    float kq[SPLIT];                                  // full prefetch: pressure
#pragma unroll                                        // flat (kq dies as a grows)
    for (int i = 0; i < SPLIT; ++i) kq[i] = rcp[(size_t)i * TF];

    float a[ORD + 1];
    a[0] = 1.0f;
    Step<1, SPLIT, 0, SPLIT>::run(a, kq);

    // state -> final out positions; per-lane strided dword stores
    float* op = out + (size_t)col * (ORD + 1);
#pragma unroll
    for (int j = 1; j <= SPLIT; ++j) op[j] = a[j];
}

// =====================  Kernel B: steps SPLIT+1..128  =====================
// ~27KB text. Reads state back, finishes, writes full rows via the proven
// conflict-free LDS transpose (stride 129 -> bank stride 1).
__global__ __launch_bounds__(128)
void lpc_stepB(const float* __restrict__ rc, float* out) {
    const int tid = threadIdx.x;
    const int col = blockIdx.x * 128 + tid;
    const int b = col >> 13;
    const int t = col & (TF - 1);
    const float* rcp = rc + ((size_t)b * ORD) * TF + t;

    constexpr int NK = ORD - SPLIT;                   // 38 remaining k's
    float kq[NK];
#pragma unroll
    for (int i = 0; i < NK; ++i) kq[i] = rcp[(size_t)(SPLIT + i) * TF];

    float a[ORD + 1];
    a[0] = 1.0f;
    {   // reload state from final out positions (per-lane strided dwords)
        const float* op = out + (size_t)col * (ORD + 1);
#pragma unroll
        for (int j = 1; j <= SPLIT; ++j) a[j] = op[j];
    }

    Step<SPLIT + 1, ORD, SPLIT, NK>::run(a, kq);

    // ---- epilogue: transpose 128 rows x 129 cols through LDS, 2 rounds ----
    __shared__ __align__(16) float lds[64 * (ORD + 1)];   // 33,024 B
    const int my_round = tid >> 6;                    // wave index, uniform branch
    const int row      = tid & 63;

    for (int r = 0; r < 2; ++r) {
        __syncthreads();
        if (my_round == r)
            Stage<0>::run(&lds[row * (ORD + 1)], a);
        __syncthreads();
        const float4* lds4 = (const float4*)lds;
        float4* out4 = (float4*)(out + (size_t)(blockIdx.x * 128 + r * 64) * (ORD + 1));
#pragma unroll 4
        for (int e = tid; e < (64 * (ORD + 1)) / 4; e += 128)
            out4[e] = lds4[e];                        // perfectly coalesced
    }
}

extern "C" void kernel_launch(void* const* d_in, const int* in_sizes, int n_in,
                              void* d_out, int out_size, void* d_ws, size_t ws_size,
                              hipStream_t stream) {
    // d_in[0] = excitation (dead in reference), d_in[1] = rc
    const float* rc = (const float*)d_in[1];
    float* out = (float*)d_out;
    hipLaunchKernelGGL(lpc_stepA, dim3((NB * TF) / 256), dim3(256), 0, stream, rc, out);
    hipLaunchKernelGGL(lpc_stepB, dim3((NB * TF) / 128), dim3(128), 0, stream, rc, out);
}

// Round 5
// 145.254 us; speedup vs baseline: 1.2233x; 1.2233x over previous
//
#include <hip/hip_runtime.h>

// LatticeFilter: step-up (Levinson-Durbin) recursion, rc -> LPC coeffs.
//   rc: (B=16, p=128, Tf=8192) fp32, k_i = 0.98*rc[b,i,t]
//   out: (B, Tf, p+1=129) fp32, a[...,0]=1
//
// R10. R9 post-mortem: dropping amdgpu_waves_per_eu reverted the backend to
// its default 8-wave/EU occupancy target -> VGPR 60/88 for a ~180/~130 live
// set -> scratch spills (A's WRITE inflated 46->50MB), both kernels ~90us
// latency-bound. The split/fmac idea was never tested; the register budget
// must be pinned in EVERY variant.
//
// Standing evidence (R8): code <=13KB runs at the BW floor; 57KB and 65KB
// run identically slow -> per-wave I-streaming from L2 dominates (~1000
// lines x ~150cy, few outstanding, 8 desynced streams thrashing the
// per-CU 32KB L1I).
//
// R10 fix: AMORTIZE THE I-STREAM ACROSS WAVES instead of shrinking the
// code. L1I is per-CU, shared by all 4 SIMDs. Launch ONE 512-thread block
// per CU (grid=256; the 132KB LDS allocation makes a second block per CU
// impossible -> guaranteed 1:1 spread) and keep its 8 waves marching in
// lockstep with a bare s_barrier every 4 steps (32 barriers, window <=4KB
// << 32KB L1I): each I-line is fetched from L2 once per CU and L1I-hits
// for the other 7 waves. Raw __builtin_amdgcn_s_barrier() -- NOT
// __syncthreads() -- so no vmcnt(0) drain: prefetched k-loads stay in
// flight across barriers. Recursion body identical to R5/R6 (bit-identical
// results). No split, no state round-trip: traffic stays at the 134.7MB
// minimum (fetch mostly L3-absorbed).
// Budget: issue 14.6us + shared I-fetch ~3-8us + epilogue ~11us ~= 27-33us.

#define NB   16
#define ORD  128
#define TF   8192

// ---- pair update j <-> m-j, both reading pre-step values (tmp-swap) ----
template<int M, int J>
struct PairUpd {
    static __device__ __forceinline__ void run(float (&a)[ORD + 1], float k) {
        const float lo = a[J];
        const float hi = a[M - J];
        a[J]     = fmaf(k, hi, lo);
        a[M - J] = fmaf(k, lo, hi);
        if constexpr (2 * (J + 1) < M) PairUpd<M, J + 1>::run(a, k);
    }
};

template<int M>
struct Step {
    static __device__ __forceinline__ void run(float (&a)[ORD + 1],
                                               const float (&kq)[ORD]) {
        const float k = 0.98f * kq[M - 1];
        if constexpr (M > 2) PairUpd<M, 1>::run(a, k);
        if constexpr ((M & 1) == 0) {            // middle element self-update
            const float mid = a[M / 2];
            a[M / 2] = fmaf(k, mid, mid);
        }
        a[M] = k;                                // a[0] == 1 contributes k
        // lockstep marker: bare barrier (no waitcnt drain), every 4 steps.
        // keeps all 8 waves of the CU inside one <=4KB I$ window.
        if constexpr ((M & 3) == 0 && M < ORD) __builtin_amdgcn_s_barrier();
        if constexpr (M < ORD) Step<M + 1>::run(a, kq);
    }
};

// ---- LDS staging, static indices (compiler merges into ds_write_b128) ----
template<int J>
struct Stage {
    static __device__ __forceinline__ void run(float* __restrict__ dst,
                                               const float (&a)[ORD + 1]) {
        dst[J] = a[J];
        if constexpr (J < ORD) Stage<J + 1>::run(dst, a);
    }
};

__global__ __launch_bounds__(512)
__attribute__((amdgpu_waves_per_eu(2, 2)))   // pin 256-reg budget (R9 lesson)
void lpc_stepup_kernel(const float* __restrict__ rc, float* __restrict__ out) {
    const int tid = threadIdx.x;
    const int col = blockIdx.x * 512 + tid;   // flattened (B*Tf) column
    const int b = col >> 13;                  // col / TF (uniform per block)
    const int t = col & (TF - 1);             // col % TF
    const float* rcp = rc + ((size_t)b * ORD) * TF + t;

    // ---- full k prefetch: pressure flat (kq[i] dies as a[i+1] is born) ----
    float kq[ORD];
#pragma unroll
    for (int i = 0; i < ORD; ++i) kq[i] = rcp[(size_t)i * TF];

    float a[ORD + 1];
    a[0] = 1.0f;
    Step<1>::run(a, kq);                      // straight-line, barrier-marched

    // ---- epilogue: transpose 512 rows x 129 cols through LDS, 2 rounds ----
    // stage: bank stride 1 (129 mod 32 = 1) -> free 2-way wave64 aliasing
    // store: 8256 contiguous float4 per round -> every line written whole
    // 132,096 B LDS also guarantees <=1 block/CU (2x132 > 160KB pool).
    __shared__ __align__(16) float lds[256 * (ORD + 1)];
    const int rnd = tid >> 8;                 // 0/1: which round I stage in
    const int row = tid & 255;

    for (int r = 0; r < 2; ++r) {
        __syncthreads();
        if (rnd == r)
            Stage<0>::run(&lds[row * (ORD + 1)], a);
        __syncthreads();
        const float4* lds4 = (const float4*)lds;
        float4* out4 = (float4*)(out + (size_t)(blockIdx.x * 512 + r * 256) * (ORD + 1));
        for (int e = tid; e < (256 * (ORD + 1)) / 4; e += 512)
            out4[e] = lds4[e];                // perfectly coalesced
    }
}

extern "C" void kernel_launch(void* const* d_in, const int* in_sizes, int n_in,
                              void* d_out, int out_size, void* d_ws, size_t ws_size,
                              hipStream_t stream) {
    // d_in[0] = excitation (dead in reference), d_in[1] = rc
    const float* rc = (const float*)d_in[1];
    float* out = (float*)d_out;
    dim3 grid((NB * TF) / 512);   // 256 blocks = one per CU (LDS-enforced)
    dim3 block(512);
    hipLaunchKernelGGL(lpc_stepup_kernel, grid, block, 0, stream, rc, out);
}